// Round 16
// baseline (3670.177 us; speedup 1.0000x reference)
//
#include <hip/hip_runtime.h>

#define L_SEQ 512
#define NB    64
#define DDIM  512
#define HHALF 256
#define GG    1024   // 4*HALF

using f32x4  = __attribute__((ext_vector_type(4))) float;
using bf16x8 = __attribute__((ext_vector_type(8))) short;
using f16x8  = __attribute__((ext_vector_type(8))) _Float16;

__device__ __forceinline__ unsigned short f2bf(float f) {
    unsigned u = __float_as_uint(f);
    u += 0x7fffu + ((u >> 16) & 1u);          // round-to-nearest-even
    return (unsigned short)(u >> 16);
}
__device__ __forceinline__ float fsigmoid(float x) {
    return 1.0f / (1.0f + __expf(-x));
}
__device__ __forceinline__ float ftanh(float x) {
    return 1.0f - 2.0f / (__expf(2.0f * x) + 1.0f);
}

// ---------------------------------------------------------------------------
// Phase 1: xwb[dir][t][b][g] (fp16) = x[t][b][:] . W_ih[g][:] + b_ih[g] + b_hh[g]
// f16 MFMA GEMM (verified config, unchanged). Additionally, blocks with
// blockIdx.y==0 pre-convert W_hh tiles 56..63 (the per-wave STREAM tiles of
// lstm_recur) to bf16 in kt-major fragment layout in workspace — done here so
// the dispatch boundary guarantees visibility to lstm_recur.
// wsc layout: [dir][wave 0..7][4096 shorts], short index
//   idx = kt*512 + q*128 + c*8 + j  <->  W_hh[(56+wave)*16 + c][kt*32+q*8+j]
// ---------------------------------------------------------------------------
__global__ __launch_bounds__(256) void gemm_xwb(
    const float* __restrict__ x,
    const float* __restrict__ Wf, const float* __restrict__ Wb,
    const float* __restrict__ bihf, const float* __restrict__ bhhf,
    const float* __restrict__ bihb, const float* __restrict__ bhhb,
    const float* __restrict__ Whhf, const float* __restrict__ Whhb,
    _Float16* __restrict__ xwb,
    unsigned short* __restrict__ wsc)
{
    const int dir = blockIdx.z;
    const float* __restrict__ W   = dir ? Wb   : Wf;
    const float* __restrict__ bih = dir ? bihb : bihf;
    const float* __restrict__ bhh = dir ? bhhb : bhhf;

    if (blockIdx.y == 0) {
        const float* __restrict__ Whh = dir ? Whhb : Whhf;
#pragma unroll
        for (int w2 = 0; w2 < 2; ++w2) {
            const int wv = blockIdx.x * 2 + w2;           // 0..7
            const int n  = 56 + wv;
            unsigned short* dst = wsc + ((size_t)dir * 8 + wv) * 4096;
            for (int idx = threadIdx.x; idx < 4096; idx += 256) {
                const int j  = idx & 7;
                const int cc = (idx >> 3) & 15;
                const int qq = (idx >> 7) & 3;
                const int kt = idx >> 9;
                dst[idx] = f2bf(Whh[(size_t)(n * 16 + cc) * HHALF + kt * 32 + qq * 8 + j]);
            }
        }
    }

    const int tid = threadIdx.x;
    const int w   = tid >> 6;                  // wave -> col group
    const int l   = tid & 63;
    const int q   = l >> 4;                    // k-subchunk / acc row group
    const int c   = l & 15;                    // frag row (A) / frag col (B,D)

    const int m0 = blockIdx.y * 64;            // 512 m-blocks
    const int n0 = blockIdx.x * 256 + w * 64;  // 4 n-blocks x 4 waves

    const float* xa = x + (size_t)(m0 + c) * DDIM + q * 8;
    const float* wa = W + (size_t)(n0 + c) * DDIM + q * 8;

    f32x4 acc[4][4];
#pragma unroll
    for (int rb = 0; rb < 4; ++rb)
#pragma unroll
        for (int nb = 0; nb < 4; ++nb) {
            f32x4 z; z[0] = 0.f; z[1] = 0.f; z[2] = 0.f; z[3] = 0.f;
            acc[rb][nb] = z;
        }

#pragma unroll 2
    for (int k0 = 0; k0 < DDIM; k0 += 32) {
        f16x8 afrag[4], bfrag[4];
#pragma unroll
        for (int rb = 0; rb < 4; ++rb) {
            const float4* p = (const float4*)(xa + (size_t)rb * 16 * DDIM + k0);
            float4 u0 = p[0], u1 = p[1];
            f16x8 v;
            v[0] = (_Float16)u0.x; v[1] = (_Float16)u0.y;
            v[2] = (_Float16)u0.z; v[3] = (_Float16)u0.w;
            v[4] = (_Float16)u1.x; v[5] = (_Float16)u1.y;
            v[6] = (_Float16)u1.z; v[7] = (_Float16)u1.w;
            afrag[rb] = v;
        }
#pragma unroll
        for (int nb = 0; nb < 4; ++nb) {
            const float4* p = (const float4*)(wa + (size_t)nb * 16 * DDIM + k0);
            float4 u0 = p[0], u1 = p[1];
            f16x8 v;
            v[0] = (_Float16)u0.x; v[1] = (_Float16)u0.y;
            v[2] = (_Float16)u0.z; v[3] = (_Float16)u0.w;
            v[4] = (_Float16)u1.x; v[5] = (_Float16)u1.y;
            v[6] = (_Float16)u1.z; v[7] = (_Float16)u1.w;
            bfrag[nb] = v;
        }
#pragma unroll
        for (int rb = 0; rb < 4; ++rb)
#pragma unroll
            for (int nb = 0; nb < 4; ++nb)
                acc[rb][nb] = __builtin_amdgcn_mfma_f32_16x16x32_f16(
                    afrag[rb], bfrag[nb], acc[rb][nb], 0, 0, 0);
    }

    // epilogue: + (b_ih + b_hh), cast fp16, store
#pragma unroll
    for (int nb = 0; nb < 4; ++nb) {
        const int col = n0 + nb * 16 + c;
        const float bias = bih[col] + bhh[col];
#pragma unroll
        for (int rb = 0; rb < 4; ++rb)
#pragma unroll
            for (int r = 0; r < 4; ++r) {
                const int m = m0 + rb * 16 + q * 4 + r;
                xwb[((size_t)dir * (L_SEQ * NB) + m) * GG + col] =
                    (_Float16)(acc[rb][nb][r] + bias);
            }
    }
}

// ---------------------------------------------------------------------------
// Phase 2: recurrence — ZERO inter-block communication.
// The LSTM recurrence is batch-row independent, so each block owns
// (dir, 16 batch rows) COMPLETELY: all 256 h-cols live in the block's LDS.
// 8 blocks x 512 threads (8 waves). One __syncthreads per step.
//
// Work decomposition: 64 N-tiles (16 gate-cols each) x K=256; wave w owns
// tiles n = w + 8i, i=0..7 (i>>1 = gate, jt = w + 8*(i&1)), so each wave
// holds all 4 gates for its two j-col tiles -> elementwise is wave-local.
// Weight residency per wave (W_hh slice 4KBx8 tiles... 8KB/tile):
//   i=0..4 : VGPR   (bfrag[5][8] bf16x8 = 160 VGPRs)
//   i=5,6  : LDS    (16 slots x 8KB = 128KB, written once at init)
//   i=7    : STREAM (re-loaded each step from wsc bf16 cache, L2-resident)
// LDS/stream/h layouts are kt-major: short idx = kt*512 + q*128 + c*8 (+j),
// giving even bank-phase distribution for ds_read_b128.
// h: s_h[2][4096] double-buffer (read phase p, write p^1) -> 1 barrier/step.
// acc is initialized from xwb (gates = xW + b + h@W^T), loads issued at step
// start; out written directly (plain f32 stores, no ordering needed).
// ---------------------------------------------------------------------------
__global__ __launch_bounds__(512, 2) void lstm_recur(
    const _Float16* __restrict__ xwb,
    const float* __restrict__ Whh_f,
    const float* __restrict__ Whh_b,
    const float* __restrict__ mask,
    const unsigned short* __restrict__ wsc,
    float* __restrict__ out)
{
    const int bid = blockIdx.x;           // 0..7
    const int dir = bid >> 2;
    const int b0  = (bid & 3) * 16;       // this block's batch rows

    const int tid = threadIdx.x;
    const int w   = tid >> 6;             // 0..7
    const int l   = tid & 63;
    const int q   = l >> 4;
    const int c   = l & 15;

    extern __shared__ char lds_raw[];     // 147456 B = 16KB h + 128KB weights
    short* s_h = (short*)lds_raw;                  // [2][4096]
    short* s_w = (short*)(lds_raw + 16384);        // [16][4096]

    const float* __restrict__ Whh = dir ? Whh_b : Whh_f;

    // ---- zero h phase 0 (h_{-1} = 0) ----
    for (int i = tid; i < 4096; i += 512) s_h[i] = 0;

    const int hoff = q * 128 + c * 8;     // lane's short-offset within a kt row

    // ---- REG weight tiles i=0..4 ----
    bf16x8 bfrag[5][8];
#pragma unroll
    for (int i = 0; i < 5; ++i) {
        const int n = w + 8 * i;
#pragma unroll
        for (int kt = 0; kt < 8; ++kt) {
            const float* wp = Whh + (size_t)(n * 16 + c) * HHALF + kt * 32 + q * 8;
            float4 w0 = ((const float4*)wp)[0], w1 = ((const float4*)wp)[1];
            bf16x8 v;
            v[0] = (short)f2bf(w0.x); v[1] = (short)f2bf(w0.y);
            v[2] = (short)f2bf(w0.z); v[3] = (short)f2bf(w0.w);
            v[4] = (short)f2bf(w1.x); v[5] = (short)f2bf(w1.y);
            v[6] = (short)f2bf(w1.z); v[7] = (short)f2bf(w1.w);
            bfrag[i][kt] = v;
        }
    }
    // ---- LDS weight tiles i=5,6 -> slots w*2+0, w*2+1 ----
#pragma unroll
    for (int s2 = 0; s2 < 2; ++s2) {
        const int n = w + 8 * (5 + s2);
#pragma unroll
        for (int kt = 0; kt < 8; ++kt) {
            const float* wp = Whh + (size_t)(n * 16 + c) * HHALF + kt * 32 + q * 8;
            float4 w0 = ((const float4*)wp)[0], w1 = ((const float4*)wp)[1];
            bf16x8 v;
            v[0] = (short)f2bf(w0.x); v[1] = (short)f2bf(w0.y);
            v[2] = (short)f2bf(w0.z); v[3] = (short)f2bf(w0.w);
            v[4] = (short)f2bf(w1.x); v[5] = (short)f2bf(w1.y);
            v[6] = (short)f2bf(w1.z); v[7] = (short)f2bf(w1.w);
            *(bf16x8*)&s_w[(w * 2 + s2) * 4096 + kt * 512 + hoff] = v;
        }
    }
    __syncthreads();

    const unsigned short* sbase = wsc + ((size_t)dir * 8 + w) * 4096 + hoff;
    const short* swp0 = &s_w[(w * 2 + 0) * 4096 + hoff];
    const short* swp1 = &s_w[(w * 2 + 1) * 4096 + hoff];

    float cstate[2][4] = {{0.f, 0.f, 0.f, 0.f}, {0.f, 0.f, 0.f, 0.f}};

    for (int step = 0; step < L_SEQ; ++step) {
        const int tt = dir ? (L_SEQ - 1 - step) : step;
        const int p  = step & 1;

        // ---- acc init from xwb: 32 scalar f16 loads, fly under kt-loop ----
        const _Float16* xp = xwb + ((size_t)(dir * L_SEQ + tt) * NB + b0 + q * 4) * GG + c;
        f32x4 acc[8];
#pragma unroll
        for (int i = 0; i < 8; ++i) {
            const int goff = (w + 8 * i) * 16;
            f32x4 a;
#pragma unroll
            for (int r = 0; r < 4; ++r)
                a[r] = (float)xp[(size_t)r * GG + goff];
            acc[i] = a;
        }

        // ---- stream batch A (kt 0..3) ----
        bf16x8 sf[4];
#pragma unroll
        for (int t = 0; t < 4; ++t)
            sf[t] = *(const bf16x8*)(sbase + t * 512);

        float mv[4];
#pragma unroll
        for (int r = 0; r < 4; ++r) mv[r] = mask[tt * NB + b0 + q * 4 + r];

        const short* hrd = &s_h[p * 4096 + hoff];

        // ---- kt 0..3 ----
#pragma unroll
        for (int kt = 0; kt < 4; ++kt) {
            bf16x8 af = *(const bf16x8*)(hrd + kt * 512);
#pragma unroll
            for (int i = 0; i < 5; ++i)
                acc[i] = __builtin_amdgcn_mfma_f32_16x16x32_bf16(af, bfrag[i][kt], acc[i], 0, 0, 0);
            bf16x8 b5 = *(const bf16x8*)(swp0 + kt * 512);
            acc[5] = __builtin_amdgcn_mfma_f32_16x16x32_bf16(af, b5, acc[5], 0, 0, 0);
            bf16x8 b6 = *(const bf16x8*)(swp1 + kt * 512);
            acc[6] = __builtin_amdgcn_mfma_f32_16x16x32_bf16(af, b6, acc[6], 0, 0, 0);
            acc[7] = __builtin_amdgcn_mfma_f32_16x16x32_bf16(af, sf[kt], acc[7], 0, 0, 0);
        }
        // ---- stream batch B (kt 4..7), reuse sf ----
#pragma unroll
        for (int t = 0; t < 4; ++t)
            sf[t] = *(const bf16x8*)(sbase + (4 + t) * 512);
        // ---- kt 4..7 ----
#pragma unroll
        for (int kt = 4; kt < 8; ++kt) {
            bf16x8 af = *(const bf16x8*)(hrd + kt * 512);
#pragma unroll
            for (int i = 0; i < 5; ++i)
                acc[i] = __builtin_amdgcn_mfma_f32_16x16x32_bf16(af, bfrag[i][kt], acc[i], 0, 0, 0);
            bf16x8 b5 = *(const bf16x8*)(swp0 + kt * 512);
            acc[5] = __builtin_amdgcn_mfma_f32_16x16x32_bf16(af, b5, acc[5], 0, 0, 0);
            bf16x8 b6 = *(const bf16x8*)(swp1 + kt * 512);
            acc[6] = __builtin_amdgcn_mfma_f32_16x16x32_bf16(af, b6, acc[6], 0, 0, 0);
            acc[7] = __builtin_amdgcn_mfma_f32_16x16x32_bf16(af, sf[kt - 4], acc[7], 0, 0, 0);
        }

        // ---- elementwise (wave-local: jt = w and w+8 have all 4 gates) ----
        short* hwr = &s_h[(p ^ 1) * 4096];
#pragma unroll
        for (int ji = 0; ji < 2; ++ji) {
            const int jt = w + 8 * ji;
#pragma unroll
            for (int r = 0; r < 4; ++r) {
                float gi = acc[0 + ji][r], gf = acc[2 + ji][r];
                float gg = acc[4 + ji][r], go = acc[6 + ji][r];
                float cn = fsigmoid(gf) * cstate[ji][r] + fsigmoid(gi) * ftanh(gg);
                float h  = fsigmoid(go) * ftanh(cn);
                float m  = mv[r];
                h  *= m;
                cn *= m;
                cstate[ji][r] = cn;
                const int bl = q * 4 + r;
                const int j  = jt * 16 + c;
                hwr[(j >> 5) * 512 + ((j >> 3) & 3) * 128 + bl * 8 + (j & 7)] = (short)f2bf(h);
                out[((size_t)tt * NB + b0 + bl) * (2 * HHALF) + dir * HHALF + j] = h;
            }
        }

        __syncthreads();   // h(p^1) complete before next step reads it
    }
}

// ---------------------------------------------------------------------------
// Workspace layout:
//   [0, 128 MiB)          xwb fp16 [2][512][64][1024]
//   [128 MiB, +128 KiB)   wsc bf16 stream-tile cache [2 dirs][8 waves][8 KiB]
// Requires ws_size >= 134,348,800 bytes (within the previously verified
// 134,349,824 budget).
// ---------------------------------------------------------------------------
extern "C" void kernel_launch(void* const* d_in, const int* in_sizes, int n_in,
                              void* d_out, int out_size, void* d_ws, size_t ws_size,
                              hipStream_t stream)
{
    (void)in_sizes; (void)n_in; (void)out_size; (void)ws_size;
    const float* x     = (const float*)d_in[0];
    const float* mask  = (const float*)d_in[1];
    const float* Wih_f = (const float*)d_in[2];
    const float* Whh_f = (const float*)d_in[3];
    const float* bih_f = (const float*)d_in[4];
    const float* bhh_f = (const float*)d_in[5];
    const float* Wih_b = (const float*)d_in[6];
    const float* Whh_b = (const float*)d_in[7];
    const float* bih_b = (const float*)d_in[8];
    const float* bhh_b = (const float*)d_in[9];
    float* out = (float*)d_out;

    _Float16*       xwb = (_Float16*)d_ws;
    unsigned short* wsc = (unsigned short*)((char*)d_ws + (size_t)2 * L_SEQ * NB * GG * sizeof(_Float16));

    hipLaunchKernelGGL(gemm_xwb, dim3(4, 512, 2), dim3(256), 0, stream,
                       x, Wih_f, Wih_b, bih_f, bhh_f, bih_b, bhh_b,
                       Whh_f, Whh_b, xwb, wsc);

    hipLaunchKernelGGL(lstm_recur, dim3(8), dim3(512), 147456, stream,
                       xwb, Whh_f, Whh_b, mask, wsc, out);
}

// Round 18
// 2405.997 us; speedup vs baseline: 1.5254x; 1.5254x over previous
//
#include <hip/hip_runtime.h>

#define L_SEQ 512
#define NB    64
#define DDIM  512
#define HHALF 256
#define GG    1024   // 4*HALF

using f32x4  = __attribute__((ext_vector_type(4))) float;
using bf16x8 = __attribute__((ext_vector_type(8))) short;
using f16x8  = __attribute__((ext_vector_type(8))) _Float16;

__device__ __forceinline__ unsigned short f2bf(float f) {
    unsigned u = __float_as_uint(f);
    u += 0x7fffu + ((u >> 16) & 1u);          // round-to-nearest-even
    return (unsigned short)(u >> 16);
}
__device__ __forceinline__ float fsigmoid(float x) {
    return 1.0f / (1.0f + __expf(-x));
}
__device__ __forceinline__ float ftanh(float x) {
    return 1.0f - 2.0f / (__expf(2.0f * x) + 1.0f);
}

// --- device-coherent (memory-side L3) access helpers -----------------------
__device__ __forceinline__ void st_short_wt(unsigned short* p, unsigned int v) {
    asm volatile("global_store_short %0, %1, off sc0 sc1" :: "v"(p), "v"(v) : "memory");
}
__device__ __forceinline__ void st_dword_wt(unsigned int* p, unsigned int v) {
    asm volatile("global_store_dword %0, %1, off sc0 sc1" :: "v"(p), "v"(v) : "memory");
}

// ---------------------------------------------------------------------------
// Phase 1: xwb[dir][t][b][g] (fp16) = x[t][b][:] . W_ih[g][:] + b_ih[g] + b_hh[g]
// f16 MFMA GEMM — byte-identical to the 1724us-measured round-2 kernel.
// Block (0,0,0) zero-inits Hbuf + flags with write-through stores.
// ---------------------------------------------------------------------------
__global__ __launch_bounds__(256) void gemm_xwb(
    const float* __restrict__ x,
    const float* __restrict__ Wf, const float* __restrict__ Wb,
    const float* __restrict__ bihf, const float* __restrict__ bhhf,
    const float* __restrict__ bihb, const float* __restrict__ bhhb,
    _Float16* __restrict__ xwb,
    unsigned int* __restrict__ zero_base, int zero_words)
{
    const int dir = blockIdx.z;
    const float* __restrict__ W   = dir ? Wb   : Wf;
    const float* __restrict__ bih = dir ? bihb : bihf;
    const float* __restrict__ bhh = dir ? bhhb : bhhf;

    if (blockIdx.x == 0 && blockIdx.y == 0 && blockIdx.z == 0) {
        for (int i = threadIdx.x; i < zero_words; i += 256)
            st_dword_wt(zero_base + i, 0u);
    }

    const int tid = threadIdx.x;
    const int w   = tid >> 6;                  // wave -> col group
    const int l   = tid & 63;
    const int q   = l >> 4;                    // k-subchunk / acc row group
    const int c   = l & 15;                    // frag row (A) / frag col (B,D)

    const int m0 = blockIdx.y * 64;            // 512 m-blocks
    const int n0 = blockIdx.x * 256 + w * 64;  // 4 n-blocks x 4 waves

    const float* xa = x + (size_t)(m0 + c) * DDIM + q * 8;
    const float* wa = W + (size_t)(n0 + c) * DDIM + q * 8;

    f32x4 acc[4][4];
#pragma unroll
    for (int rb = 0; rb < 4; ++rb)
#pragma unroll
        for (int nb = 0; nb < 4; ++nb) {
            f32x4 z; z[0] = 0.f; z[1] = 0.f; z[2] = 0.f; z[3] = 0.f;
            acc[rb][nb] = z;
        }

#pragma unroll 2
    for (int k0 = 0; k0 < DDIM; k0 += 32) {
        f16x8 afrag[4], bfrag[4];
#pragma unroll
        for (int rb = 0; rb < 4; ++rb) {
            const float4* p = (const float4*)(xa + (size_t)rb * 16 * DDIM + k0);
            float4 u0 = p[0], u1 = p[1];
            f16x8 v;
            v[0] = (_Float16)u0.x; v[1] = (_Float16)u0.y;
            v[2] = (_Float16)u0.z; v[3] = (_Float16)u0.w;
            v[4] = (_Float16)u1.x; v[5] = (_Float16)u1.y;
            v[6] = (_Float16)u1.z; v[7] = (_Float16)u1.w;
            afrag[rb] = v;
        }
#pragma unroll
        for (int nb = 0; nb < 4; ++nb) {
            const float4* p = (const float4*)(wa + (size_t)nb * 16 * DDIM + k0);
            float4 u0 = p[0], u1 = p[1];
            f16x8 v;
            v[0] = (_Float16)u0.x; v[1] = (_Float16)u0.y;
            v[2] = (_Float16)u0.z; v[3] = (_Float16)u0.w;
            v[4] = (_Float16)u1.x; v[5] = (_Float16)u1.y;
            v[6] = (_Float16)u1.z; v[7] = (_Float16)u1.w;
            bfrag[nb] = v;
        }
#pragma unroll
        for (int rb = 0; rb < 4; ++rb)
#pragma unroll
            for (int nb = 0; nb < 4; ++nb)
                acc[rb][nb] = __builtin_amdgcn_mfma_f32_16x16x32_f16(
                    afrag[rb], bfrag[nb], acc[rb][nb], 0, 0, 0);
    }

    // epilogue: + (b_ih + b_hh), cast fp16, store
#pragma unroll
    for (int nb = 0; nb < 4; ++nb) {
        const int col = n0 + nb * 16 + c;
        const float bias = bih[col] + bhh[col];
#pragma unroll
        for (int rb = 0; rb < 4; ++rb)
#pragma unroll
            for (int r = 0; r < 4; ++r) {
                const int m = m0 + rb * 16 + q * 4 + r;
                xwb[((size_t)dir * (L_SEQ * NB) + m) * GG + col] =
                    (_Float16)(acc[rb][nb][r] + bias);
            }
    }
}

// ---------------------------------------------------------------------------
// Phase 2: recurrence — round-2 structure (measured 1724 us) with ONE change:
// the per-group shared atomic counter (16 RMWs/step onto one hot line,
// serialized at the L3 atomic unit against 16 spinning readers) is replaced
// by PER-WAVE FLAG SLOTS with plain write-through stores:
//  * flags[grp][gw] (gw = slice*4 + wave, 16 dwords = one 64B segment/group;
//    groups padded to 128B). flag value = number of completed steps.
//  * publish: after vmcnt(0) (h stores acked at coherent point), lane 0
//    stores flag = step+1 via sc0|sc1 dword store — NO RMW, no return, no
//    atomic-unit serialization.
//  * acquire: all 64 lanes load flags[grp][l&15] (ONE coalesced 64B request
//    per poll iteration — not 64 lines like round-15's data-poll), loop
//    until __all(flag >= step). flag>=s <=> wave completed step s-1, and a
//    wave publishes s only after its phase-(s&1) reads, so the double-buffer
//    recycling induction is unchanged from the verified round-2 scheme.
// Everything else (Hbuf double-buffer, sc0|sc1 h-stores, xwb prefetch,
// out-after-publish) is byte-identical to the 1724us kernel, so the bench
// delta isolates the RMW->plain-store swap.
// ---------------------------------------------------------------------------
__global__ __launch_bounds__(256, 1) void lstm_recur(
    const _Float16* __restrict__ xwb,
    const float* __restrict__ Whh_f,
    const float* __restrict__ Whh_b,
    const float* __restrict__ mask,
    float* __restrict__ out,
    unsigned short* __restrict__ Hbuf,    // [phase][dir][64][256] bf16
    unsigned int* __restrict__ flags)     // [8 groups][32 uints, 16 used]
{
    const int bid = blockIdx.x;           // 0..31
    const int grp = bid & 7;              // dir*4 + gb
    const int dir = grp >> 2;
    const int gb  = grp & 3;
    const int g   = bid >> 3;             // h-col slice 0..3

    const int tid = threadIdx.x;
    const int w   = tid >> 6;
    const int l   = tid & 63;
    const int q   = l >> 4;
    const int c   = l & 15;

    const int b0 = gb * 16;               // group's batch base
    const int j  = 64 * g + 16 * w + c;   // h column [0,256)
    const int gw = g * 4 + w;             // wave id within group, 0..15

    unsigned int* gflags = flags + grp * 32;

    // --- B fragments: W_hh slice, register resident ---
    const float* __restrict__ Whh = dir ? Whh_b : Whh_f;
    bf16x8 bfrag[4][8];
#pragma unroll
    for (int t = 0; t < 4; ++t) {
        const int gcol = t * HHALF + j;
#pragma unroll
        for (int kt = 0; kt < 8; ++kt) {
            const float4* wp = (const float4*)(Whh + (size_t)gcol * HHALF + kt * 32 + q * 8);
            float4 w0 = wp[0], w1 = wp[1];
            bf16x8 v;
            v[0] = (short)f2bf(w0.x); v[1] = (short)f2bf(w0.y);
            v[2] = (short)f2bf(w0.z); v[3] = (short)f2bf(w0.w);
            v[4] = (short)f2bf(w1.x); v[5] = (short)f2bf(w1.y);
            v[6] = (short)f2bf(w1.z); v[7] = (short)f2bf(w1.w);
            bfrag[t][kt] = v;
        }
    }

    float cstate[4] = {0.f, 0.f, 0.f, 0.f};

    for (int step = 0; step < L_SEQ; ++step) {
        const int tt = dir ? (L_SEQ - 1 - step) : step;

        // ---- prefetch (independent of h): xwb + mask for this step ----
        float xv[4][4];
        const _Float16* xp = xwb + ((size_t)(dir * L_SEQ + tt) * NB + b0 + q * 4) * GG + j;
#pragma unroll
        for (int t = 0; t < 4; ++t)
#pragma unroll
            for (int r = 0; r < 4; ++r)
                xv[t][r] = (float)xp[(size_t)r * GG + t * HHALF];
        float mv[4];
#pragma unroll
        for (int r = 0; r < 4; ++r) mv[r] = mask[tt * NB + b0 + q * 4 + r];

        // ---- per-wave wait: lane l polls flags[grp][l&15]; one coalesced
        //      64B request per iteration; no RMW anywhere ----
        {
            const unsigned target = (unsigned)step;
            unsigned int* fp = gflags + (l & 15);
            for (;;) {
                unsigned v;
                asm volatile("global_load_dword %0, %1, off sc0 sc1\n\t"
                             "s_waitcnt vmcnt(0)"
                             : "=v"(v) : "v"(fp) : "memory");
                __builtin_amdgcn_sched_barrier(0);   // rule #18
                if (__all(v >= target)) break;
            }
        }

        const unsigned short* __restrict__ Hr =
            Hbuf + (size_t)((step & 1) * 2 + dir) * NB * HHALF;
        unsigned short* __restrict__ Hw =
            Hbuf + (size_t)(((step + 1) & 1) * 2 + dir) * NB * HHALF;

        // ---- A fragments: h rows b0..b0+15, full K=256, coherent loads ----
        bf16x8 afrag[8];
        const unsigned short* hp = Hr + (size_t)(b0 + c) * HHALF;
#pragma unroll
        for (int kt = 0; kt < 8; ++kt) {
            const unsigned short* p = hp + kt * 32 + q * 8;
            asm volatile("global_load_dwordx4 %0, %1, off sc0 sc1"
                         : "=&v"(afrag[kt]) : "v"(p));
        }
        asm volatile("s_waitcnt vmcnt(0)" ::: "memory");
        __builtin_amdgcn_sched_barrier(0);   // rule #18

        // ---- gates = xW (+biases) + h @ W_hh^T ----
        f32x4 acc[4];
#pragma unroll
        for (int t = 0; t < 4; ++t) {
            f32x4 a; a[0] = xv[t][0]; a[1] = xv[t][1]; a[2] = xv[t][2]; a[3] = xv[t][3];
            acc[t] = a;
        }
#pragma unroll
        for (int kt = 0; kt < 8; ++kt)
#pragma unroll
            for (int t = 0; t < 4; ++t)
                acc[t] = __builtin_amdgcn_mfma_f32_16x16x32_bf16(afrag[kt], bfrag[t][kt], acc[t], 0, 0, 0);

        // ---- elementwise: lane holds i,f,g,o for (b0+q*4+r, j) ----
        float hval[4];
#pragma unroll
        for (int r = 0; r < 4; ++r) {
            float gi = acc[0][r], gf = acc[1][r], gg = acc[2][r], go = acc[3][r];
            float cn = fsigmoid(gf) * cstate[r] + fsigmoid(gi) * ftanh(gg);
            float h  = fsigmoid(go) * ftanh(cn);
            float m  = mv[r];
            h  *= m;
            cn *= m;
            cstate[r] = cn;
            hval[r]   = h;
            st_short_wt(Hw + (size_t)(b0 + q * 4 + r) * HHALF + j,
                        (unsigned int)f2bf(h));
        }

        // ---- publish: wait own store acks, ONE plain flag store per wave ----
        asm volatile("s_waitcnt vmcnt(0)" ::: "memory");
        __builtin_amdgcn_sched_barrier(0);
        if (l == 0)
            st_dword_wt(gflags + gw, (unsigned)(step + 1));
        __builtin_amdgcn_sched_barrier(0);   // keep out-stores below the publish

        // ---- out stores: off the critical path (drain under next poll) ----
#pragma unroll
        for (int r = 0; r < 4; ++r) {
            const int b = b0 + q * 4 + r;
            out[((size_t)tt * NB + b) * (2 * HHALF) + dir * HHALF + j] = hval[r];
        }
    }
}

// ---------------------------------------------------------------------------
// Workspace layout:
//   [0, 128 MiB)            xwb   fp16 [2][512][64][1024]
//   [+0,   +128 KiB)        Hbuf  bf16 [2 phases][2 dirs][64][256]
//   [+128K, +1 KiB)         flags u32 [8 groups][32]
// Requires ws_size >= 134,349,824 bytes.
// ---------------------------------------------------------------------------
extern "C" void kernel_launch(void* const* d_in, const int* in_sizes, int n_in,
                              void* d_out, int out_size, void* d_ws, size_t ws_size,
                              hipStream_t stream)
{
    (void)in_sizes; (void)n_in; (void)out_size; (void)ws_size;
    const float* x     = (const float*)d_in[0];
    const float* mask  = (const float*)d_in[1];
    const float* Wih_f = (const float*)d_in[2];
    const float* Whh_f = (const float*)d_in[3];
    const float* bih_f = (const float*)d_in[4];
    const float* bhh_f = (const float*)d_in[5];
    const float* Wih_b = (const float*)d_in[6];
    const float* Whh_b = (const float*)d_in[7];
    const float* bih_b = (const float*)d_in[8];
    const float* bhh_b = (const float*)d_in[9];
    float* out = (float*)d_out;

    const size_t xwb_bytes  = (size_t)2 * L_SEQ * NB * GG * sizeof(_Float16);
    const size_t hbuf_bytes = (size_t)2 * 2 * NB * HHALF * sizeof(unsigned short);
    _Float16*       xwb   = (_Float16*)d_ws;
    unsigned short* Hbuf  = (unsigned short*)((char*)d_ws + xwb_bytes);
    unsigned int*   flags = (unsigned int*)((char*)d_ws + xwb_bytes + hbuf_bytes);

    // gemm_xwb also zero-inits Hbuf + flags (33,024 words) from block (0,0,0)
    const int zero_words = (int)((hbuf_bytes + 8 * 32 * sizeof(unsigned int)) / 4);
    hipLaunchKernelGGL(gemm_xwb, dim3(4, 512, 2), dim3(256), 0, stream,
                       x, Wih_f, Wih_b, bih_f, bhh_f, bih_b, bhh_b, xwb,
                       (unsigned int*)Hbuf, zero_words);

    hipLaunchKernelGGL(lstm_recur, dim3(32), dim3(256), 0, stream,
                       xwb, Whh_f, Whh_b, mask, out, Hbuf, flags);
}